// Round 1
// baseline (794.396 us; speedup 1.0000x reference)
//
#include <hip/hip_runtime.h>
#include <hip/hip_bf16.h>
#include <math.h>

#define S_LEN 2048
#define HIDW 2048
#define NHEAD 16
#define NKVH 4
#define HD 128
#define NB 2
#define MROWS (NB * S_LEN)                 // 4096
#define QKVN (NHEAD * HD + 2 * NKVH * HD)  // 3072
#define KOFF (NHEAD * HD)                  // 2048
#define VOFF (NHEAD * HD + NKVH * HD)      // 2560

typedef __bf16 bf16_t;
typedef __bf16 bf16x8_t __attribute__((ext_vector_type(8)));
typedef float f32x4_t __attribute__((ext_vector_type(4)));

__device__ __forceinline__ void gload_lds16(const bf16_t* g, bf16_t* l) {
  __builtin_amdgcn_global_load_lds(
      (const __attribute__((address_space(1))) void*)g,
      (__attribute__((address_space(3))) void*)l, 16, 0, 0);
}

__device__ __forceinline__ f32x4_t zero4() {
  f32x4_t z = {0.f, 0.f, 0.f, 0.f};
  return z;
}

// ---------------- convert x (f32 -> bf16), 8 elems/thread ----------------
__global__ __launch_bounds__(256) void k_cvt8(const float* __restrict__ in,
                                              bf16_t* __restrict__ out, int n8) {
  int i = blockIdx.x * 256 + threadIdx.x;
  if (i >= n8) return;
  const float4* p = (const float4*)(in + (size_t)i * 8);
  float4 a = p[0], b = p[1];
  bf16x8_t r;
  r[0] = (bf16_t)a.x; r[1] = (bf16_t)a.y; r[2] = (bf16_t)a.z; r[3] = (bf16_t)a.w;
  r[4] = (bf16_t)b.x; r[5] = (bf16_t)b.y; r[6] = (bf16_t)b.z; r[7] = (bf16_t)b.w;
  *(bf16x8_t*)(out + (size_t)i * 8) = r;
}

// ---------------- transpose + convert: in f32 [R][C] -> out bf16 [C][R] ----
__global__ __launch_bounds__(256) void k_tr_cvt(const float* __restrict__ in,
                                                bf16_t* __restrict__ out, int R, int C) {
  __shared__ float t[32][33];
  int c0 = blockIdx.x * 32, r0 = blockIdx.y * 32;
  int tx = threadIdx.x & 31, ty = threadIdx.x >> 5;
#pragma unroll
  for (int rr = ty; rr < 32; rr += 8) t[rr][tx] = in[(size_t)(r0 + rr) * C + c0 + tx];
  __syncthreads();
#pragma unroll
  for (int rr = ty; rr < 32; rr += 8)
    out[(size_t)(c0 + rr) * R + r0 + tx] = (bf16_t)t[tx][rr];
}

// ---------------- GEMM: C[M][N] = A[M][K] * Bt[N][K]^T (m97 structure) -----
template <int OUTF32>
__global__ __launch_bounds__(256) void k_gemm_bt(const bf16_t* __restrict__ A,
                                                 const bf16_t* __restrict__ Bt,
                                                 void* __restrict__ Cout,
                                                 int M, int N, int K) {
  __shared__ bf16_t As[128 * 64];
  __shared__ bf16_t Bs[128 * 64];
  int tid = threadIdx.x;
  int lane = tid & 63;
  int row0 = blockIdx.x * 128, col0 = blockIdx.y * 128;
  int wid = tid >> 6;
  int wr = (wid >> 1) * 64, wc = (wid & 1) * 64;
  int l15 = lane & 15, lg = lane >> 4;

  f32x4_t acc[4][4];
#pragma unroll
  for (int i = 0; i < 4; i++)
#pragma unroll
    for (int j = 0; j < 4; j++) acc[i][j] = zero4();

  int srow = tid >> 3;            // 0..31
  int scol = (tid & 7) * 8;       // 0..56
  const bf16_t* ag = A + (size_t)(row0 + srow) * K + scol;
  const bf16_t* bg = Bt + (size_t)(col0 + srow) * K + scol;
  bf16_t* as = As + srow * 64 + scol;
  bf16_t* bs = Bs + srow * 64 + scol;

  for (int k0 = 0; k0 < K; k0 += 64) {
    __syncthreads();
#pragma unroll
    for (int i = 0; i < 4; i++) {
      gload_lds16(ag + (size_t)(32 * i) * K + k0, as + 32 * i * 64);
      gload_lds16(bg + (size_t)(32 * i) * K + k0, bs + 32 * i * 64);
    }
    __syncthreads();
#pragma unroll
    for (int kk = 0; kk < 2; kk++) {
      bf16x8_t af[4], bfr[4];
#pragma unroll
      for (int i = 0; i < 4; i++) {
        af[i] = *(const bf16x8_t*)(As + (wr + i * 16 + l15) * 64 + kk * 32 + lg * 8);
        bfr[i] = *(const bf16x8_t*)(Bs + (wc + i * 16 + l15) * 64 + kk * 32 + lg * 8);
      }
#pragma unroll
      for (int i = 0; i < 4; i++)
#pragma unroll
        for (int j = 0; j < 4; j++)
          acc[i][j] = __builtin_amdgcn_mfma_f32_16x16x32_bf16(af[i], bfr[j], acc[i][j], 0, 0, 0);
    }
  }
#pragma unroll
  for (int i = 0; i < 4; i++) {
#pragma unroll
    for (int j = 0; j < 4; j++) {
      int r = row0 + wr + i * 16 + lg * 4;
      int c = col0 + wc + j * 16 + l15;
#pragma unroll
      for (int q = 0; q < 4; q++) {
        if (OUTF32)
          ((float*)Cout)[(size_t)(r + q) * N + c] = acc[i][j][q];
        else
          ((bf16_t*)Cout)[(size_t)(r + q) * N + c] = (bf16_t)acc[i][j][q];
      }
    }
  }
}

// ---------------- RoPE (interleaved), in-place on qkv submatrix ------------
__global__ __launch_bounds__(256) void k_rope(bf16_t* __restrict__ buf,
                                              const float* __restrict__ cosT,
                                              const float* __restrict__ sinT,
                                              int ncols, float scale) {
  int idx = blockIdx.x * 256 + threadIdx.x;
  int perrow = ncols >> 3;
  int row = idx / perrow;
  int c8 = (idx - row * perrow) << 3;
  int s = row & (S_LEN - 1);
  int p0 = (c8 & (HD - 1)) >> 1;
  bf16_t* p = buf + (size_t)row * QKVN + c8;
  bf16x8_t v = *(const bf16x8_t*)p;
  bf16x8_t r;
#pragma unroll
  for (int t = 0; t < 4; t++) {
    float c = cosT[s * 64 + p0 + t];
    float sn = sinT[s * 64 + p0 + t];
    float te = (float)v[2 * t], to = (float)v[2 * t + 1];
    r[2 * t] = (bf16_t)((te * c - to * sn) * scale);
    r[2 * t + 1] = (bf16_t)((to * c + te * sn) * scale);
  }
  *(bf16x8_t*)p = r;
}

// ---------------- V -> Vt relayout: vt[b][kvh][d][s] -----------------------
__global__ __launch_bounds__(256) void k_vt(const bf16_t* __restrict__ qkv,
                                            bf16_t* __restrict__ vt) {
  __shared__ bf16_t t[32][33];
  int s0 = blockIdx.x * 32;
  int dt = (blockIdx.y & 3) * 32;
  int h = blockIdx.y >> 2;
  int b = blockIdx.z;
  int tx = threadIdx.x & 31, ty = threadIdx.x >> 5;
#pragma unroll
  for (int rr = ty; rr < 32; rr += 8)
    t[rr][tx] = qkv[(size_t)(b * S_LEN + s0 + rr) * QKVN + VOFF + h * HD + dt + tx];
  __syncthreads();
#pragma unroll
  for (int rr = ty; rr < 32; rr += 8)
    vt[((size_t)((b * NKVH + h) * HD + dt + rr)) * S_LEN + s0 + tx] = t[tx][rr];
}

// ---------------- flash attention: 1 wave = 16 q rows ----------------------
__global__ __launch_bounds__(256) void k_attn(const bf16_t* __restrict__ qkv,
                                              const bf16_t* __restrict__ vt,
                                              bf16_t* __restrict__ ctx) {
  __shared__ bf16_t plds[4][16 * 72];
  int lane = threadIdx.x & 63, wid = threadIdx.x >> 6;
  int widx = blockIdx.x * 4 + wid;
  int qt = widx & 127;
  int bh = widx >> 7;
  int b = bh >> 4, h = bh & 15;
  int kvh = h >> 2;
  int q0 = qt * 16;
  int l15 = lane & 15, lg = lane >> 4;

  const bf16_t* Qp = qkv + (size_t)(b * S_LEN + q0 + l15) * QKVN + h * HD + lg * 8;
  bf16x8_t aq[4];
#pragma unroll
  for (int kk = 0; kk < 4; kk++) aq[kk] = *(const bf16x8_t*)(Qp + kk * 32);

  f32x4_t o[8];
#pragma unroll
  for (int j = 0; j < 8; j++) o[j] = zero4();
  float m[4], lsum[4];
#pragma unroll
  for (int i = 0; i < 4; i++) { m[i] = -INFINITY; lsum[i] = 0.f; }

  const bf16_t* Kbase = qkv + (size_t)(b * S_LEN) * QKVN + KOFF + kvh * HD;
  const bf16_t* Vbase = vt + (size_t)(b * NKVH + kvh) * HD * S_LEN;
  bf16_t* pbuf = &plds[wid][0];

  int ntiles = (q0 + 16 + 63) >> 6;
  for (int t = 0; t < ntiles; t++) {
    int kv0 = t * 64;
    f32x4_t sacc[4];
#pragma unroll
    for (int cg = 0; cg < 4; cg++) sacc[cg] = zero4();
#pragma unroll
    for (int cg = 0; cg < 4; cg++) {
      const bf16_t* Kp = Kbase + (size_t)(kv0 + cg * 16 + l15) * QKVN + lg * 8;
#pragma unroll
      for (int kk = 0; kk < 4; kk++) {
        bf16x8_t bk = *(const bf16x8_t*)(Kp + kk * 32);
        sacc[cg] = __builtin_amdgcn_mfma_f32_16x16x32_bf16(aq[kk], bk, sacc[cg], 0, 0, 0);
      }
    }
    if (kv0 + 63 > q0) {
#pragma unroll
      for (int cg = 0; cg < 4; cg++) {
        int col = kv0 + cg * 16 + l15;
#pragma unroll
        for (int i = 0; i < 4; i++) {
          int row = q0 + lg * 4 + i;
          if (col > row) sacc[cg][i] = -1e30f;
        }
      }
    }
#pragma unroll
    for (int i = 0; i < 4; i++) {
      float v = fmaxf(fmaxf(sacc[0][i], sacc[1][i]), fmaxf(sacc[2][i], sacc[3][i]));
      v = fmaxf(v, __shfl_xor(v, 1));
      v = fmaxf(v, __shfl_xor(v, 2));
      v = fmaxf(v, __shfl_xor(v, 4));
      v = fmaxf(v, __shfl_xor(v, 8));
      float nm = fmaxf(m[i], v);
      float sc = __expf(m[i] - nm);
      m[i] = nm;
      lsum[i] *= sc;
#pragma unroll
      for (int j = 0; j < 8; j++) o[j][i] *= sc;
    }
#pragma unroll
    for (int cg = 0; cg < 4; cg++)
#pragma unroll
      for (int i = 0; i < 4; i++) sacc[cg][i] = __expf(sacc[cg][i] - m[i]);
#pragma unroll
    for (int i = 0; i < 4; i++) {
      float s = sacc[0][i] + sacc[1][i] + sacc[2][i] + sacc[3][i];
      s += __shfl_xor(s, 1);
      s += __shfl_xor(s, 2);
      s += __shfl_xor(s, 4);
      s += __shfl_xor(s, 8);
      lsum[i] += s;
    }
#pragma unroll
    for (int cg = 0; cg < 4; cg++)
#pragma unroll
      for (int i = 0; i < 4; i++)
        pbuf[(lg * 4 + i) * 72 + cg * 16 + l15] = (bf16_t)sacc[cg][i];
    __builtin_amdgcn_wave_barrier();
    bf16x8_t pa0 = *(const bf16x8_t*)(pbuf + l15 * 72 + lg * 8);
    bf16x8_t pa1 = *(const bf16x8_t*)(pbuf + l15 * 72 + 32 + lg * 8);
    __builtin_amdgcn_wave_barrier();
#pragma unroll
    for (int j = 0; j < 8; j++) {
      const bf16_t* Vp = Vbase + (size_t)(j * 16 + l15) * S_LEN + kv0 + lg * 8;
      o[j] = __builtin_amdgcn_mfma_f32_16x16x32_bf16(pa0, *(const bf16x8_t*)(Vp), o[j], 0, 0, 0);
      o[j] = __builtin_amdgcn_mfma_f32_16x16x32_bf16(pa1, *(const bf16x8_t*)(Vp + 32), o[j], 0, 0, 0);
    }
  }
  bf16_t* Cp = ctx + (size_t)(b * S_LEN + q0) * KOFF + h * HD;
#pragma unroll
  for (int i = 0; i < 4; i++) {
    float inv = 1.f / lsum[i];
    int row = lg * 4 + i;
#pragma unroll
    for (int j = 0; j < 8; j++)
      Cp[(size_t)row * KOFF + j * 16 + l15] = (bf16_t)(o[j][i] * inv);
  }
}

extern "C" void kernel_launch(void* const* d_in, const int* in_sizes, int n_in,
                              void* d_out, int out_size, void* d_ws, size_t ws_size,
                              hipStream_t stream) {
  const float* x = (const float*)d_in[0];
  const float* wq = (const float*)d_in[1];
  const float* wk = (const float*)d_in[2];
  const float* wv = (const float*)d_in[3];
  const float* wo = (const float*)d_in[4];
  const float* cosT = (const float*)d_in[5];
  const float* sinT = (const float*)d_in[6];

  bf16_t* xb = (bf16_t*)d_ws;                          // 4096x2048 (later reused as ctx)
  bf16_t* wqkvT = xb + (size_t)MROWS * HIDW;           // 3072x2048
  bf16_t* woT = wqkvT + (size_t)QKVN * HIDW;           // 2048x2048
  bf16_t* qkv = woT + (size_t)HIDW * HIDW;             // 4096x3072
  bf16_t* vtb = qkv + (size_t)MROWS * QKVN;            // 2*4*128*2048

  // 1) convert x
  k_cvt8<<<MROWS * HIDW / 8 / 256, 256, 0, stream>>>(x, xb, MROWS * HIDW / 8);
  // 2) weight transposes (f32 -> bf16, [K][N] -> [N][K])
  k_tr_cvt<<<dim3(KOFF / 32, HIDW / 32), 256, 0, stream>>>(wq, wqkvT, HIDW, KOFF);
  k_tr_cvt<<<dim3((NKVH * HD) / 32, HIDW / 32), 256, 0, stream>>>(
      wk, wqkvT + (size_t)KOFF * HIDW, HIDW, NKVH * HD);
  k_tr_cvt<<<dim3((NKVH * HD) / 32, HIDW / 32), 256, 0, stream>>>(
      wv, wqkvT + (size_t)VOFF * HIDW, HIDW, NKVH * HD);
  k_tr_cvt<<<dim3(HIDW / 32, KOFF / 32), 256, 0, stream>>>(wo, woT, KOFF, HIDW);
  // 3) QKV projection
  k_gemm_bt<0><<<dim3(MROWS / 128, QKVN / 128), 256, 0, stream>>>(
      xb, wqkvT, qkv, MROWS, QKVN, HIDW);
  // 4) RoPE on q (fold 1/sqrt(D)) and k
  k_rope<<<MROWS * KOFF / 8 / 256, 256, 0, stream>>>(qkv, cosT, sinT, KOFF,
                                                     0.08838834764831845f);
  k_rope<<<MROWS * (NKVH * HD) / 8 / 256, 256, 0, stream>>>(qkv + KOFF, cosT, sinT,
                                                            NKVH * HD, 1.0f);
  // 5) V transpose
  k_vt<<<dim3(S_LEN / 32, 4 * NKVH, NB), 256, 0, stream>>>(qkv, vtb);
  // 6) attention (ctx written into xb region — xb no longer needed)
  k_attn<<<(NB * NHEAD * (S_LEN / 16)) / 4, 256, 0, stream>>>(qkv, vtb, xb);
  // 7) output projection -> f32 d_out
  k_gemm_bt<1><<<dim3(MROWS / 128, HIDW / 128), 256, 0, stream>>>(
      xb, woT, d_out, MROWS, HIDW, KOFF);
}

// Round 2
// 458.029 us; speedup vs baseline: 1.7344x; 1.7344x over previous
//
#include <hip/hip_runtime.h>
#include <hip/hip_bf16.h>
#include <math.h>

#define S_LEN 2048
#define HIDW 2048
#define NHEAD 16
#define NKVH 4
#define HD 128
#define NB 2
#define MROWS (NB * S_LEN)                 // 4096
#define QKVN (NHEAD * HD + 2 * NKVH * HD)  // 3072
#define KOFF (NHEAD * HD)                  // 2048
#define VOFF (NHEAD * HD + NKVH * HD)      // 2560

typedef __bf16 bf16_t;
typedef __bf16 bf16x8_t __attribute__((ext_vector_type(8)));
typedef float f32x4_t __attribute__((ext_vector_type(4)));

__device__ __forceinline__ void gload_lds16(const bf16_t* g, bf16_t* l) {
  __builtin_amdgcn_global_load_lds(
      (const __attribute__((address_space(1))) void*)g,
      (__attribute__((address_space(3))) void*)l, 16, 0, 0);
}

__device__ __forceinline__ f32x4_t zero4() {
  f32x4_t z = {0.f, 0.f, 0.f, 0.f};
  return z;
}

// ---------------- convert x (f32 -> bf16), 8 elems/thread ----------------
__global__ __launch_bounds__(256) void k_cvt8(const float* __restrict__ in,
                                              bf16_t* __restrict__ out, int n8) {
  int i = blockIdx.x * 256 + threadIdx.x;
  if (i >= n8) return;
  const float4* p = (const float4*)(in + (size_t)i * 8);
  float4 a = p[0], b = p[1];
  bf16x8_t r;
  r[0] = (bf16_t)a.x; r[1] = (bf16_t)a.y; r[2] = (bf16_t)a.z; r[3] = (bf16_t)a.w;
  r[4] = (bf16_t)b.x; r[5] = (bf16_t)b.y; r[6] = (bf16_t)b.z; r[7] = (bf16_t)b.w;
  *(bf16x8_t*)(out + (size_t)i * 8) = r;
}

// ---------------- transpose + convert: in f32 [R][C] -> out bf16 [C][R] ----
__global__ __launch_bounds__(256) void k_tr_cvt(const float* __restrict__ in,
                                                bf16_t* __restrict__ out, int R, int C) {
  __shared__ float t[32][33];
  int c0 = blockIdx.x * 32, r0 = blockIdx.y * 32;
  int tx = threadIdx.x & 31, ty = threadIdx.x >> 5;
#pragma unroll
  for (int rr = ty; rr < 32; rr += 8) t[rr][tx] = in[(size_t)(r0 + rr) * C + c0 + tx];
  __syncthreads();
#pragma unroll
  for (int rr = ty; rr < 32; rr += 8)
    out[(size_t)(c0 + rr) * R + r0 + tx] = (bf16_t)t[tx][rr];
}

// ---------------- GEMM: C[M][N] = A[M][K] * Bt[N][K]^T (m97 structure) -----
template <int OUTF32>
__global__ __launch_bounds__(256) void k_gemm_bt(const bf16_t* __restrict__ A,
                                                 const bf16_t* __restrict__ Bt,
                                                 void* __restrict__ Cout,
                                                 int M, int N, int K) {
  __shared__ bf16_t As[128 * 64];
  __shared__ bf16_t Bs[128 * 64];
  int tid = threadIdx.x;
  int lane = tid & 63;
  int row0 = blockIdx.x * 128, col0 = blockIdx.y * 128;
  int wid = tid >> 6;
  int wr = (wid >> 1) * 64, wc = (wid & 1) * 64;
  int l15 = lane & 15, lg = lane >> 4;

  f32x4_t acc[4][4];
#pragma unroll
  for (int i = 0; i < 4; i++)
#pragma unroll
    for (int j = 0; j < 4; j++) acc[i][j] = zero4();

  int srow = tid >> 3;            // 0..31
  int scol = (tid & 7) * 8;       // 0..56
  const bf16_t* ag = A + (size_t)(row0 + srow) * K + scol;
  const bf16_t* bg = Bt + (size_t)(col0 + srow) * K + scol;
  bf16_t* as = As + srow * 64 + scol;
  bf16_t* bs = Bs + srow * 64 + scol;

  for (int k0 = 0; k0 < K; k0 += 64) {
    __syncthreads();
#pragma unroll
    for (int i = 0; i < 4; i++) {
      gload_lds16(ag + (size_t)(32 * i) * K + k0, as + 32 * i * 64);
      gload_lds16(bg + (size_t)(32 * i) * K + k0, bs + 32 * i * 64);
    }
    __syncthreads();
#pragma unroll
    for (int kk = 0; kk < 2; kk++) {
      bf16x8_t af[4], bfr[4];
#pragma unroll
      for (int i = 0; i < 4; i++) {
        af[i] = *(const bf16x8_t*)(As + (wr + i * 16 + l15) * 64 + kk * 32 + lg * 8);
        bfr[i] = *(const bf16x8_t*)(Bs + (wc + i * 16 + l15) * 64 + kk * 32 + lg * 8);
      }
#pragma unroll
      for (int i = 0; i < 4; i++)
#pragma unroll
        for (int j = 0; j < 4; j++)
          acc[i][j] = __builtin_amdgcn_mfma_f32_16x16x32_bf16(af[i], bfr[j], acc[i][j], 0, 0, 0);
    }
  }
#pragma unroll
  for (int i = 0; i < 4; i++) {
#pragma unroll
    for (int j = 0; j < 4; j++) {
      int r = row0 + wr + i * 16 + lg * 4;
      int c = col0 + wc + j * 16 + l15;
#pragma unroll
      for (int q = 0; q < 4; q++) {
        if (OUTF32)
          ((float*)Cout)[(size_t)(r + q) * N + c] = acc[i][j][q];
        else
          ((bf16_t*)Cout)[(size_t)(r + q) * N + c] = (bf16_t)acc[i][j][q];
      }
    }
  }
}

// ---------------- RoPE (interleaved), in-place on qkv submatrix ------------
__global__ __launch_bounds__(256) void k_rope(bf16_t* __restrict__ buf,
                                              const float* __restrict__ cosT,
                                              const float* __restrict__ sinT,
                                              int ncols, float scale) {
  int idx = blockIdx.x * 256 + threadIdx.x;
  int perrow = ncols >> 3;
  int row = idx / perrow;
  int c8 = (idx - row * perrow) << 3;
  int s = row & (S_LEN - 1);
  int p0 = (c8 & (HD - 1)) >> 1;
  bf16_t* p = buf + (size_t)row * QKVN + c8;
  bf16x8_t v = *(const bf16x8_t*)p;
  bf16x8_t r;
#pragma unroll
  for (int t = 0; t < 4; t++) {
    float c = cosT[s * 64 + p0 + t];
    float sn = sinT[s * 64 + p0 + t];
    float te = (float)v[2 * t], to = (float)v[2 * t + 1];
    r[2 * t] = (bf16_t)((te * c - to * sn) * scale);
    r[2 * t + 1] = (bf16_t)((to * c + te * sn) * scale);
  }
  *(bf16x8_t*)p = r;
}

// ---------------- V -> Vt relayout: vt[b][kvh][d][s] -----------------------
__global__ __launch_bounds__(256) void k_vt(const bf16_t* __restrict__ qkv,
                                            bf16_t* __restrict__ vt) {
  __shared__ bf16_t t[32][33];
  int s0 = blockIdx.x * 32;
  int dt = (blockIdx.y & 3) * 32;
  int h = blockIdx.y >> 2;
  int b = blockIdx.z;
  int tx = threadIdx.x & 31, ty = threadIdx.x >> 5;
#pragma unroll
  for (int rr = ty; rr < 32; rr += 8)
    t[rr][tx] = qkv[(size_t)(b * S_LEN + s0 + rr) * QKVN + VOFF + h * HD + dt + tx];
  __syncthreads();
#pragma unroll
  for (int rr = ty; rr < 32; rr += 8)
    vt[((size_t)((b * NKVH + h) * HD + dt + rr)) * S_LEN + s0 + tx] = t[tx][rr];
}

// ---------------- flash attention: 1 wave = 16 q rows ----------------------
// Work-balanced mapping: bh fastest in blockIdx, q-group slowest; within a
// block the 4 waves take q-tiles at stride 32 so every block's lifetime is
// ~uniform (25..33 KV tiles) regardless of dispatch order. (Old mapping put
// same-work blocks on the same CU -> 11.8% occupancy.)
__global__ __launch_bounds__(256) void k_attn(const bf16_t* __restrict__ qkv,
                                              const bf16_t* __restrict__ vt,
                                              bf16_t* __restrict__ ctx) {
  __shared__ bf16_t plds[4][16 * 72];
  int lane = threadIdx.x & 63, wid = threadIdx.x >> 6;
  int bh = blockIdx.x & 31;   // b*NHEAD+h packed: b = bh>>4, h = bh&15
  int qg = blockIdx.x >> 5;   // 0..31
  int qt = wid * 32 + qg;     // 0..127
  int b = bh >> 4, h = bh & 15;
  int kvh = h >> 2;
  int q0 = qt * 16;
  int l15 = lane & 15, lg = lane >> 4;

  const bf16_t* Qp = qkv + (size_t)(b * S_LEN + q0 + l15) * QKVN + h * HD + lg * 8;
  bf16x8_t aq[4];
#pragma unroll
  for (int kk = 0; kk < 4; kk++) aq[kk] = *(const bf16x8_t*)(Qp + kk * 32);

  f32x4_t o[8];
#pragma unroll
  for (int j = 0; j < 8; j++) o[j] = zero4();
  float m[4], lsum[4];
#pragma unroll
  for (int i = 0; i < 4; i++) { m[i] = -INFINITY; lsum[i] = 0.f; }

  const bf16_t* Kbase = qkv + (size_t)(b * S_LEN) * QKVN + KOFF + kvh * HD;
  const bf16_t* Vbase = vt + (size_t)(b * NKVH + kvh) * HD * S_LEN;
  bf16_t* pbuf = &plds[wid][0];

  int ntiles = (q0 + 16 + 63) >> 6;
  for (int t = 0; t < ntiles; t++) {
    int kv0 = t * 64;
    // hoist all 16 K-fragment loads: 16 independent L2 gathers in flight
    bf16x8_t kf[4][4];
#pragma unroll
    for (int cg = 0; cg < 4; cg++) {
      const bf16_t* Kp = Kbase + (size_t)(kv0 + cg * 16 + l15) * QKVN + lg * 8;
#pragma unroll
      for (int kk = 0; kk < 4; kk++) kf[cg][kk] = *(const bf16x8_t*)(Kp + kk * 32);
    }
    f32x4_t sacc[4];
#pragma unroll
    for (int cg = 0; cg < 4; cg++) sacc[cg] = zero4();
#pragma unroll
    for (int cg = 0; cg < 4; cg++)
#pragma unroll
      for (int kk = 0; kk < 4; kk++)
        sacc[cg] = __builtin_amdgcn_mfma_f32_16x16x32_bf16(aq[kk], kf[cg][kk], sacc[cg], 0, 0, 0);
    if (kv0 + 63 > q0) {
#pragma unroll
      for (int cg = 0; cg < 4; cg++) {
        int col = kv0 + cg * 16 + l15;
#pragma unroll
        for (int i = 0; i < 4; i++) {
          int row = q0 + lg * 4 + i;
          if (col > row) sacc[cg][i] = -1e30f;
        }
      }
    }
#pragma unroll
    for (int i = 0; i < 4; i++) {
      float v = fmaxf(fmaxf(sacc[0][i], sacc[1][i]), fmaxf(sacc[2][i], sacc[3][i]));
      v = fmaxf(v, __shfl_xor(v, 1));
      v = fmaxf(v, __shfl_xor(v, 2));
      v = fmaxf(v, __shfl_xor(v, 4));
      v = fmaxf(v, __shfl_xor(v, 8));
      float nm = fmaxf(m[i], v);
      float sc = __expf(m[i] - nm);
      m[i] = nm;
      lsum[i] *= sc;
#pragma unroll
      for (int j = 0; j < 8; j++) o[j][i] *= sc;
    }
#pragma unroll
    for (int cg = 0; cg < 4; cg++)
#pragma unroll
      for (int i = 0; i < 4; i++) sacc[cg][i] = __expf(sacc[cg][i] - m[i]);
#pragma unroll
    for (int i = 0; i < 4; i++) {
      float s = sacc[0][i] + sacc[1][i] + sacc[2][i] + sacc[3][i];
      s += __shfl_xor(s, 1);
      s += __shfl_xor(s, 2);
      s += __shfl_xor(s, 4);
      s += __shfl_xor(s, 8);
      lsum[i] += s;
    }
#pragma unroll
    for (int cg = 0; cg < 4; cg++)
#pragma unroll
      for (int i = 0; i < 4; i++)
        pbuf[(lg * 4 + i) * 72 + cg * 16 + l15] = (bf16_t)sacc[cg][i];
    __builtin_amdgcn_wave_barrier();
    bf16x8_t pa0 = *(const bf16x8_t*)(pbuf + l15 * 72 + lg * 8);
    bf16x8_t pa1 = *(const bf16x8_t*)(pbuf + l15 * 72 + 32 + lg * 8);
    __builtin_amdgcn_wave_barrier();
#pragma unroll
    for (int j = 0; j < 8; j++) {
      const bf16_t* Vp = Vbase + (size_t)(j * 16 + l15) * S_LEN + kv0 + lg * 8;
      o[j] = __builtin_amdgcn_mfma_f32_16x16x32_bf16(pa0, *(const bf16x8_t*)(Vp), o[j], 0, 0, 0);
      o[j] = __builtin_amdgcn_mfma_f32_16x16x32_bf16(pa1, *(const bf16x8_t*)(Vp + 32), o[j], 0, 0, 0);
    }
  }
  bf16_t* Cp = ctx + (size_t)(b * S_LEN + q0) * KOFF + h * HD;
#pragma unroll
  for (int i = 0; i < 4; i++) {
    float inv = 1.f / lsum[i];
    int row = lg * 4 + i;
#pragma unroll
    for (int j = 0; j < 8; j++)
      Cp[(size_t)row * KOFF + j * 16 + l15] = (bf16_t)(o[j][i] * inv);
  }
}

extern "C" void kernel_launch(void* const* d_in, const int* in_sizes, int n_in,
                              void* d_out, int out_size, void* d_ws, size_t ws_size,
                              hipStream_t stream) {
  const float* x = (const float*)d_in[0];
  const float* wq = (const float*)d_in[1];
  const float* wk = (const float*)d_in[2];
  const float* wv = (const float*)d_in[3];
  const float* wo = (const float*)d_in[4];
  const float* cosT = (const float*)d_in[5];
  const float* sinT = (const float*)d_in[6];

  bf16_t* xb = (bf16_t*)d_ws;                          // 4096x2048 (later reused as ctx)
  bf16_t* wqkvT = xb + (size_t)MROWS * HIDW;           // 3072x2048
  bf16_t* woT = wqkvT + (size_t)QKVN * HIDW;           // 2048x2048
  bf16_t* qkv = woT + (size_t)HIDW * HIDW;             // 4096x3072
  bf16_t* vtb = qkv + (size_t)MROWS * QKVN;            // 2*4*128*2048

  // 1) convert x
  k_cvt8<<<MROWS * HIDW / 8 / 256, 256, 0, stream>>>(x, xb, MROWS * HIDW / 8);
  // 2) weight transposes (f32 -> bf16, [K][N] -> [N][K])
  k_tr_cvt<<<dim3(KOFF / 32, HIDW / 32), 256, 0, stream>>>(wq, wqkvT, HIDW, KOFF);
  k_tr_cvt<<<dim3((NKVH * HD) / 32, HIDW / 32), 256, 0, stream>>>(
      wk, wqkvT + (size_t)KOFF * HIDW, HIDW, NKVH * HD);
  k_tr_cvt<<<dim3((NKVH * HD) / 32, HIDW / 32), 256, 0, stream>>>(
      wv, wqkvT + (size_t)VOFF * HIDW, HIDW, NKVH * HD);
  k_tr_cvt<<<dim3(HIDW / 32, KOFF / 32), 256, 0, stream>>>(wo, woT, KOFF, HIDW);
  // 3) QKV projection
  k_gemm_bt<0><<<dim3(MROWS / 128, QKVN / 128), 256, 0, stream>>>(
      xb, wqkvT, qkv, MROWS, QKVN, HIDW);
  // 4) RoPE on q (fold 1/sqrt(D)) and k
  k_rope<<<MROWS * KOFF / 8 / 256, 256, 0, stream>>>(qkv, cosT, sinT, KOFF,
                                                     0.08838834764831845f);
  k_rope<<<MROWS * (NKVH * HD) / 8 / 256, 256, 0, stream>>>(qkv + KOFF, cosT, sinT,
                                                            NKVH * HD, 1.0f);
  // 5) V transpose
  k_vt<<<dim3(S_LEN / 32, 4 * NKVH, NB), 256, 0, stream>>>(qkv, vtb);
  // 6) attention (ctx written into xb region — xb no longer needed)
  k_attn<<<(NB * NHEAD * (S_LEN / 16)) / 4, 256, 0, stream>>>(qkv, vtb, xb);
  // 7) output projection -> f32 d_out
  k_gemm_bt<1><<<dim3(MROWS / 128, HIDW / 128), 256, 0, stream>>>(
      xb, woT, d_out, MROWS, HIDW, KOFF);
}

// Round 3
// 292.339 us; speedup vs baseline: 2.7174x; 1.5668x over previous
//
#include <hip/hip_runtime.h>
#include <hip/hip_bf16.h>
#include <math.h>

#define S_LEN 2048
#define HIDW 2048
#define NHEAD 16
#define NKVH 4
#define HD 128
#define NB 2
#define MROWS (NB * S_LEN)                 // 4096
#define QKVN (NHEAD * HD + 2 * NKVH * HD)  // 3072
#define KOFF (NHEAD * HD)                  // 2048
#define VOFF (NHEAD * HD + NKVH * HD)      // 2560

typedef __bf16 bf16_t;
typedef __bf16 bf16x8_t __attribute__((ext_vector_type(8)));
typedef float f32x4_t __attribute__((ext_vector_type(4)));

__device__ __forceinline__ void gload_lds16(const bf16_t* g, bf16_t* l) {
  __builtin_amdgcn_global_load_lds(
      (const __attribute__((address_space(1))) void*)g,
      (__attribute__((address_space(3))) void*)l, 16, 0, 0);
}

__device__ __forceinline__ f32x4_t zero4() {
  f32x4_t z = {0.f, 0.f, 0.f, 0.f};
  return z;
}

// ---------------- convert x (f32 -> bf16), 8 elems/thread ----------------
__global__ __launch_bounds__(256) void k_cvt8(const float* __restrict__ in,
                                              bf16_t* __restrict__ out, int n8) {
  int i = blockIdx.x * 256 + threadIdx.x;
  if (i >= n8) return;
  const float4* p = (const float4*)(in + (size_t)i * 8);
  float4 a = p[0], b = p[1];
  bf16x8_t r;
  r[0] = (bf16_t)a.x; r[1] = (bf16_t)a.y; r[2] = (bf16_t)a.z; r[3] = (bf16_t)a.w;
  r[4] = (bf16_t)b.x; r[5] = (bf16_t)b.y; r[6] = (bf16_t)b.z; r[7] = (bf16_t)b.w;
  *(bf16x8_t*)(out + (size_t)i * 8) = r;
}

// ---------------- transpose + convert: in f32 [R][C] -> out bf16 [C][R] ----
__global__ __launch_bounds__(256) void k_tr_cvt(const float* __restrict__ in,
                                                bf16_t* __restrict__ out, int R, int C) {
  __shared__ float t[32][33];
  int c0 = blockIdx.x * 32, r0 = blockIdx.y * 32;
  int tx = threadIdx.x & 31, ty = threadIdx.x >> 5;
#pragma unroll
  for (int rr = ty; rr < 32; rr += 8) t[rr][tx] = in[(size_t)(r0 + rr) * C + c0 + tx];
  __syncthreads();
#pragma unroll
  for (int rr = ty; rr < 32; rr += 8)
    out[(size_t)(c0 + rr) * R + r0 + tx] = (bf16_t)t[tx][rr];
}

// ---------------- GEMM: C[M][N] = A[M][K] * Bt[N][K]^T (m97 structure) -----
template <int OUTF32>
__global__ __launch_bounds__(256) void k_gemm_bt(const bf16_t* __restrict__ A,
                                                 const bf16_t* __restrict__ Bt,
                                                 void* __restrict__ Cout,
                                                 int M, int N, int K) {
  __shared__ bf16_t As[128 * 64];
  __shared__ bf16_t Bs[128 * 64];
  int tid = threadIdx.x;
  int lane = tid & 63;
  int row0 = blockIdx.x * 128, col0 = blockIdx.y * 128;
  int wid = tid >> 6;
  int wr = (wid >> 1) * 64, wc = (wid & 1) * 64;
  int l15 = lane & 15, lg = lane >> 4;

  f32x4_t acc[4][4];
#pragma unroll
  for (int i = 0; i < 4; i++)
#pragma unroll
    for (int j = 0; j < 4; j++) acc[i][j] = zero4();

  int srow = tid >> 3;            // 0..31
  int scol = (tid & 7) * 8;       // 0..56
  const bf16_t* ag = A + (size_t)(row0 + srow) * K + scol;
  const bf16_t* bg = Bt + (size_t)(col0 + srow) * K + scol;
  bf16_t* as = As + srow * 64 + scol;
  bf16_t* bs = Bs + srow * 64 + scol;

  for (int k0 = 0; k0 < K; k0 += 64) {
    __syncthreads();
#pragma unroll
    for (int i = 0; i < 4; i++) {
      gload_lds16(ag + (size_t)(32 * i) * K + k0, as + 32 * i * 64);
      gload_lds16(bg + (size_t)(32 * i) * K + k0, bs + 32 * i * 64);
    }
    __syncthreads();
#pragma unroll
    for (int kk = 0; kk < 2; kk++) {
      bf16x8_t af[4], bfr[4];
#pragma unroll
      for (int i = 0; i < 4; i++) {
        af[i] = *(const bf16x8_t*)(As + (wr + i * 16 + l15) * 64 + kk * 32 + lg * 8);
        bfr[i] = *(const bf16x8_t*)(Bs + (wc + i * 16 + l15) * 64 + kk * 32 + lg * 8);
      }
#pragma unroll
      for (int i = 0; i < 4; i++)
#pragma unroll
        for (int j = 0; j < 4; j++)
          acc[i][j] = __builtin_amdgcn_mfma_f32_16x16x32_bf16(af[i], bfr[j], acc[i][j], 0, 0, 0);
    }
  }
#pragma unroll
  for (int i = 0; i < 4; i++) {
#pragma unroll
    for (int j = 0; j < 4; j++) {
      int r = row0 + wr + i * 16 + lg * 4;
      int c = col0 + wc + j * 16 + l15;
#pragma unroll
      for (int q = 0; q < 4; q++) {
        if (OUTF32)
          ((float*)Cout)[(size_t)(r + q) * N + c] = acc[i][j][q];
        else
          ((bf16_t*)Cout)[(size_t)(r + q) * N + c] = (bf16_t)acc[i][j][q];
      }
    }
  }
}

// ---------------- RoPE (interleaved), in-place on qkv submatrix ------------
__global__ __launch_bounds__(256) void k_rope(bf16_t* __restrict__ buf,
                                              const float* __restrict__ cosT,
                                              const float* __restrict__ sinT,
                                              int ncols, float scale) {
  int idx = blockIdx.x * 256 + threadIdx.x;
  int perrow = ncols >> 3;
  int row = idx / perrow;
  int c8 = (idx - row * perrow) << 3;
  int s = row & (S_LEN - 1);
  int p0 = (c8 & (HD - 1)) >> 1;
  bf16_t* p = buf + (size_t)row * QKVN + c8;
  bf16x8_t v = *(const bf16x8_t*)p;
  bf16x8_t r;
#pragma unroll
  for (int t = 0; t < 4; t++) {
    float c = cosT[s * 64 + p0 + t];
    float sn = sinT[s * 64 + p0 + t];
    float te = (float)v[2 * t], to = (float)v[2 * t + 1];
    r[2 * t] = (bf16_t)((te * c - to * sn) * scale);
    r[2 * t + 1] = (bf16_t)((to * c + te * sn) * scale);
  }
  *(bf16x8_t*)p = r;
}

// ---------------- V -> Vt relayout: vt[b][kvh][d][s] -----------------------
__global__ __launch_bounds__(256) void k_vt(const bf16_t* __restrict__ qkv,
                                            bf16_t* __restrict__ vt) {
  __shared__ bf16_t t[32][33];
  int s0 = blockIdx.x * 32;
  int dt = (blockIdx.y & 3) * 32;
  int h = blockIdx.y >> 2;
  int b = blockIdx.z;
  int tx = threadIdx.x & 31, ty = threadIdx.x >> 5;
#pragma unroll
  for (int rr = ty; rr < 32; rr += 8)
    t[rr][tx] = qkv[(size_t)(b * S_LEN + s0 + rr) * QKVN + VOFF + h * HD + dt + tx];
  __syncthreads();
#pragma unroll
  for (int rr = ty; rr < 32; rr += 8)
    vt[((size_t)((b * NKVH + h) * HD + dt + rr)) * S_LEN + s0 + tx] = t[tx][rr];
}

// ---------------- flash attention: 8 waves, QBLK=128, shared K/V in LDS ----
// Block = 512 threads = 8 waves, each wave owns 16 consecutive q rows of one
// (b,h); the block covers 128 consecutive q rows so every wave needs 2qg+1 or
// 2qg+2 KV tiles (skew <= 1 tile -> waves finish together). K tile [64][128]
// and Vt tile [128][64] are staged once per block via global_load_lds with
// XOR swizzle (byte ^= (row&7)<<4) applied on BOTH sides: inverse-swizzled
// global source + swizzled ds_read (m201 pattern) -> conflict-free b128 reads.
// Grid 512 = 32 bh x 16 qg, ordered so round-robin pair {c, c+256} has
// constant work sum 34 and the SAME (b,h) -> shared K/V in L2.
__global__ __launch_bounds__(512, 4) void k_attn(const bf16_t* __restrict__ qkv,
                                                 const bf16_t* __restrict__ vt,
                                                 bf16_t* __restrict__ ctx) {
  __shared__ bf16_t Ks[64 * 128];   // 16 KB, swizzled row-major [kv][d]
  __shared__ bf16_t Vs[128 * 64];   // 16 KB, swizzled row-major [d][kv]
  __shared__ bf16_t plds[8][16 * 72];

  int tid = threadIdx.x;
  int lane = tid & 63, wid = tid >> 6;
  int idx = blockIdx.x;
  int bh = idx & 31;
  int qb = (idx >> 5) & 7;
  int g = idx >> 8;
  int qg = g ? (15 - qb) : qb;     // complementary pairing across {c, c+256}
  int b = bh >> 4, h = bh & 15;
  int kvh = h >> 2;
  int q0 = qg * 128 + wid * 16;
  int l15 = lane & 15, lg = lane >> 4;

  const bf16_t* Kbase = qkv + (size_t)(b * S_LEN) * QKVN + KOFF + kvh * HD;
  const bf16_t* Vbase = vt + (size_t)(b * NKVH + kvh) * HD * S_LEN;

  // Q fragments (16 rows x 128) -> regs
  const bf16_t* Qp = qkv + (size_t)(b * S_LEN + q0 + l15) * QKVN + h * HD + lg * 8;
  bf16x8_t aq[4];
#pragma unroll
  for (int kk = 0; kk < 4; kk++) aq[kk] = *(const bf16x8_t*)(Qp + kk * 32);

  // staging source pointers: thread covers stored bytes [L, L+16); the global
  // element for that slot is at the inverse-swizzled logical byte.
  int L0 = tid * 16, L1 = 8192 + tid * 16;
  int Lk0 = L0 ^ (((L0 >> 8) & 7) << 4);
  int Lk1 = L1 ^ (((L1 >> 8) & 7) << 4);
  int Lv0 = L0 ^ (((L0 >> 7) & 7) << 4);
  int Lv1 = L1 ^ (((L1 >> 7) & 7) << 4);
  const bf16_t* kg0 = Kbase + (size_t)(Lk0 >> 8) * QKVN + ((Lk0 & 255) >> 1);
  const bf16_t* kg1 = Kbase + (size_t)(Lk1 >> 8) * QKVN + ((Lk1 & 255) >> 1);
  const bf16_t* vg0 = Vbase + (size_t)(Lv0 >> 7) * S_LEN + ((Lv0 & 127) >> 1);
  const bf16_t* vg1 = Vbase + (size_t)(Lv1 >> 7) * S_LEN + ((Lv1 & 127) >> 1);

  f32x4_t o[8];
#pragma unroll
  for (int j = 0; j < 8; j++) o[j] = zero4();
  float m[4], lsum[4];
#pragma unroll
  for (int i = 0; i < 4; i++) { m[i] = -INFINITY; lsum[i] = 0.f; }

  bf16_t* pbuf = &plds[wid][0];
  int xr = (l15 & 7) << 4;          // read-side XOR (row low bits = l15 low bits)
  int ntiles = 2 * qg + 2;

  for (int t = 0; t < ntiles; t++) {
    int kv0 = t * 64;
    __syncthreads();
    gload_lds16(kg0, Ks + tid * 8);
    gload_lds16(kg1, Ks + 4096 + tid * 8);
    gload_lds16(vg0, Vs + tid * 8);
    gload_lds16(vg1, Vs + 4096 + tid * 8);
    kg0 += 64 * QKVN; kg1 += 64 * QKVN; vg0 += 64; vg1 += 64;
    __syncthreads();

    if (kv0 <= q0 + 15) {  // wave-uniform: skip fully-masked tiles
      // ---- QK^T ----
      f32x4_t sacc[4];
#pragma unroll
      for (int cg = 0; cg < 4; cg++) sacc[cg] = zero4();
#pragma unroll
      for (int cg = 0; cg < 4; cg++) {
#pragma unroll
        for (int kk = 0; kk < 4; kk++) {
          int boff = ((cg * 16 + l15) * 256 + kk * 64 + lg * 16) ^ xr;
          bf16x8_t bk = *(const bf16x8_t*)((const char*)Ks + boff);
          sacc[cg] = __builtin_amdgcn_mfma_f32_16x16x32_bf16(aq[kk], bk, sacc[cg], 0, 0, 0);
        }
      }
      if (kv0 + 63 > q0) {
#pragma unroll
        for (int cg = 0; cg < 4; cg++) {
          int col = kv0 + cg * 16 + l15;
#pragma unroll
          for (int i = 0; i < 4; i++) {
            int row = q0 + lg * 4 + i;
            if (col > row) sacc[cg][i] = -1e30f;
          }
        }
      }
      // ---- online softmax (wave-parallel) ----
#pragma unroll
      for (int i = 0; i < 4; i++) {
        float v = fmaxf(fmaxf(sacc[0][i], sacc[1][i]), fmaxf(sacc[2][i], sacc[3][i]));
        v = fmaxf(v, __shfl_xor(v, 1));
        v = fmaxf(v, __shfl_xor(v, 2));
        v = fmaxf(v, __shfl_xor(v, 4));
        v = fmaxf(v, __shfl_xor(v, 8));
        float nm = fmaxf(m[i], v);
        float sc = __expf(m[i] - nm);
        m[i] = nm;
        lsum[i] *= sc;
#pragma unroll
        for (int j = 0; j < 8; j++) o[j][i] *= sc;
      }
#pragma unroll
      for (int cg = 0; cg < 4; cg++)
#pragma unroll
        for (int i = 0; i < 4; i++) sacc[cg][i] = __expf(sacc[cg][i] - m[i]);
#pragma unroll
      for (int i = 0; i < 4; i++) {
        float s = sacc[0][i] + sacc[1][i] + sacc[2][i] + sacc[3][i];
        s += __shfl_xor(s, 1);
        s += __shfl_xor(s, 2);
        s += __shfl_xor(s, 4);
        s += __shfl_xor(s, 8);
        lsum[i] += s;
      }
      // ---- P -> per-wave LDS -> A-fragments ----
#pragma unroll
      for (int cg = 0; cg < 4; cg++)
#pragma unroll
        for (int i = 0; i < 4; i++)
          pbuf[(lg * 4 + i) * 72 + cg * 16 + l15] = (bf16_t)sacc[cg][i];
      __builtin_amdgcn_wave_barrier();
      bf16x8_t pa0 = *(const bf16x8_t*)(pbuf + l15 * 72 + lg * 8);
      bf16x8_t pa1 = *(const bf16x8_t*)(pbuf + l15 * 72 + 32 + lg * 8);
      __builtin_amdgcn_wave_barrier();
      // ---- P·V ----
#pragma unroll
      for (int j = 0; j < 8; j++) {
        int d = j * 16 + l15;
        int bo0 = (d * 128 + lg * 16) ^ xr;
        int bo1 = (d * 128 + 64 + lg * 16) ^ xr;
        o[j] = __builtin_amdgcn_mfma_f32_16x16x32_bf16(
            pa0, *(const bf16x8_t*)((const char*)Vs + bo0), o[j], 0, 0, 0);
        o[j] = __builtin_amdgcn_mfma_f32_16x16x32_bf16(
            pa1, *(const bf16x8_t*)((const char*)Vs + bo1), o[j], 0, 0, 0);
      }
    }
  }

  bf16_t* Cp = ctx + (size_t)(b * S_LEN + q0) * KOFF + h * HD;
#pragma unroll
  for (int i = 0; i < 4; i++) {
    float inv = 1.f / lsum[i];
    int row = lg * 4 + i;
#pragma unroll
    for (int j = 0; j < 8; j++)
      Cp[(size_t)row * KOFF + j * 16 + l15] = (bf16_t)(o[j][i] * inv);
  }
}

extern "C" void kernel_launch(void* const* d_in, const int* in_sizes, int n_in,
                              void* d_out, int out_size, void* d_ws, size_t ws_size,
                              hipStream_t stream) {
  const float* x = (const float*)d_in[0];
  const float* wq = (const float*)d_in[1];
  const float* wk = (const float*)d_in[2];
  const float* wv = (const float*)d_in[3];
  const float* wo = (const float*)d_in[4];
  const float* cosT = (const float*)d_in[5];
  const float* sinT = (const float*)d_in[6];

  bf16_t* xb = (bf16_t*)d_ws;                          // 4096x2048 (later reused as ctx)
  bf16_t* wqkvT = xb + (size_t)MROWS * HIDW;           // 3072x2048
  bf16_t* woT = wqkvT + (size_t)QKVN * HIDW;           // 2048x2048
  bf16_t* qkv = woT + (size_t)HIDW * HIDW;             // 4096x3072
  bf16_t* vtb = qkv + (size_t)MROWS * QKVN;            // 2*4*128*2048

  // 1) convert x
  k_cvt8<<<MROWS * HIDW / 8 / 256, 256, 0, stream>>>(x, xb, MROWS * HIDW / 8);
  // 2) weight transposes (f32 -> bf16, [K][N] -> [N][K])
  k_tr_cvt<<<dim3(KOFF / 32, HIDW / 32), 256, 0, stream>>>(wq, wqkvT, HIDW, KOFF);
  k_tr_cvt<<<dim3((NKVH * HD) / 32, HIDW / 32), 256, 0, stream>>>(
      wk, wqkvT + (size_t)KOFF * HIDW, HIDW, NKVH * HD);
  k_tr_cvt<<<dim3((NKVH * HD) / 32, HIDW / 32), 256, 0, stream>>>(
      wv, wqkvT + (size_t)VOFF * HIDW, HIDW, NKVH * HD);
  k_tr_cvt<<<dim3(HIDW / 32, KOFF / 32), 256, 0, stream>>>(wo, woT, KOFF, HIDW);
  // 3) QKV projection
  k_gemm_bt<0><<<dim3(MROWS / 128, QKVN / 128), 256, 0, stream>>>(
      xb, wqkvT, qkv, MROWS, QKVN, HIDW);
  // 4) RoPE on q (fold 1/sqrt(D)) and k
  k_rope<<<MROWS * KOFF / 8 / 256, 256, 0, stream>>>(qkv, cosT, sinT, KOFF,
                                                     0.08838834764831845f);
  k_rope<<<MROWS * (NKVH * HD) / 8 / 256, 256, 0, stream>>>(qkv + KOFF, cosT, sinT,
                                                            NKVH * HD, 1.0f);
  // 5) V transpose
  k_vt<<<dim3(S_LEN / 32, 4 * NKVH, NB), 256, 0, stream>>>(qkv, vtb);
  // 6) attention (ctx written into xb region — xb no longer needed)
  k_attn<<<32 * 16, 512, 0, stream>>>(qkv, vtb, xb);
  // 7) output projection -> f32 d_out
  k_gemm_bt<1><<<dim3(MROWS / 128, HIDW / 128), 256, 0, stream>>>(
      xb, woT, d_out, MROWS, HIDW, KOFF);
}

// Round 4
// 266.200 us; speedup vs baseline: 2.9842x; 1.0982x over previous
//
#include <hip/hip_runtime.h>
#include <hip/hip_bf16.h>
#include <math.h>

#define S_LEN 2048
#define HIDW 2048
#define NHEAD 16
#define NKVH 4
#define HD 128
#define NB 2
#define MROWS (NB * S_LEN)                 // 4096
#define QKVN (NHEAD * HD + 2 * NKVH * HD)  // 3072
#define KOFF (NHEAD * HD)                  // 2048
#define VOFF (NHEAD * HD + NKVH * HD)      // 2560

typedef __bf16 bf16_t;
typedef __bf16 bf16x8_t __attribute__((ext_vector_type(8)));
typedef float f32x4_t __attribute__((ext_vector_type(4)));

__device__ __forceinline__ void gload_lds16(const bf16_t* g, bf16_t* l) {
  __builtin_amdgcn_global_load_lds(
      (const __attribute__((address_space(1))) void*)g,
      (__attribute__((address_space(3))) void*)l, 16, 0, 0);
}

__device__ __forceinline__ f32x4_t zero4() {
  f32x4_t z = {0.f, 0.f, 0.f, 0.f};
  return z;
}

__device__ __forceinline__ float fexp2(float x) {
#if __has_builtin(__builtin_amdgcn_exp2f)
  return __builtin_amdgcn_exp2f(x);
#else
  return exp2f(x);
#endif
}

// ---------------- convert x (f32 -> bf16), 8 elems/thread ----------------
__global__ __launch_bounds__(256) void k_cvt8(const float* __restrict__ in,
                                              bf16_t* __restrict__ out, int n8) {
  int i = blockIdx.x * 256 + threadIdx.x;
  if (i >= n8) return;
  const float4* p = (const float4*)(in + (size_t)i * 8);
  float4 a = p[0], b = p[1];
  bf16x8_t r;
  r[0] = (bf16_t)a.x; r[1] = (bf16_t)a.y; r[2] = (bf16_t)a.z; r[3] = (bf16_t)a.w;
  r[4] = (bf16_t)b.x; r[5] = (bf16_t)b.y; r[6] = (bf16_t)b.z; r[7] = (bf16_t)b.w;
  *(bf16x8_t*)(out + (size_t)i * 8) = r;
}

// ---------------- transpose + convert: in f32 [R][C] -> out bf16 [C][R] ----
__global__ __launch_bounds__(256) void k_tr_cvt(const float* __restrict__ in,
                                                bf16_t* __restrict__ out, int R, int C) {
  __shared__ float t[32][33];
  int c0 = blockIdx.x * 32, r0 = blockIdx.y * 32;
  int tx = threadIdx.x & 31, ty = threadIdx.x >> 5;
#pragma unroll
  for (int rr = ty; rr < 32; rr += 8) t[rr][tx] = in[(size_t)(r0 + rr) * C + c0 + tx];
  __syncthreads();
#pragma unroll
  for (int rr = ty; rr < 32; rr += 8)
    out[(size_t)(c0 + rr) * R + r0 + tx] = (bf16_t)t[tx][rr];
}

// ---------------- GEMM: C[M][N] = A[M][K] * Bt[N][K]^T (m97 structure) -----
template <int OUTF32>
__global__ __launch_bounds__(256) void k_gemm_bt(const bf16_t* __restrict__ A,
                                                 const bf16_t* __restrict__ Bt,
                                                 void* __restrict__ Cout,
                                                 int M, int N, int K) {
  __shared__ bf16_t As[128 * 64];
  __shared__ bf16_t Bs[128 * 64];
  int tid = threadIdx.x;
  int lane = tid & 63;
  int row0 = blockIdx.x * 128, col0 = blockIdx.y * 128;
  int wid = tid >> 6;
  int wr = (wid >> 1) * 64, wc = (wid & 1) * 64;
  int l15 = lane & 15, lg = lane >> 4;

  f32x4_t acc[4][4];
#pragma unroll
  for (int i = 0; i < 4; i++)
#pragma unroll
    for (int j = 0; j < 4; j++) acc[i][j] = zero4();

  int srow = tid >> 3;            // 0..31
  int scol = (tid & 7) * 8;       // 0..56
  const bf16_t* ag = A + (size_t)(row0 + srow) * K + scol;
  const bf16_t* bg = Bt + (size_t)(col0 + srow) * K + scol;
  bf16_t* as = As + srow * 64 + scol;
  bf16_t* bs = Bs + srow * 64 + scol;

  for (int k0 = 0; k0 < K; k0 += 64) {
    __syncthreads();
#pragma unroll
    for (int i = 0; i < 4; i++) {
      gload_lds16(ag + (size_t)(32 * i) * K + k0, as + 32 * i * 64);
      gload_lds16(bg + (size_t)(32 * i) * K + k0, bs + 32 * i * 64);
    }
    __syncthreads();
#pragma unroll
    for (int kk = 0; kk < 2; kk++) {
      bf16x8_t af[4], bfr[4];
#pragma unroll
      for (int i = 0; i < 4; i++) {
        af[i] = *(const bf16x8_t*)(As + (wr + i * 16 + l15) * 64 + kk * 32 + lg * 8);
        bfr[i] = *(const bf16x8_t*)(Bs + (wc + i * 16 + l15) * 64 + kk * 32 + lg * 8);
      }
#pragma unroll
      for (int i = 0; i < 4; i++)
#pragma unroll
        for (int j = 0; j < 4; j++)
          acc[i][j] = __builtin_amdgcn_mfma_f32_16x16x32_bf16(af[i], bfr[j], acc[i][j], 0, 0, 0);
    }
  }
#pragma unroll
  for (int i = 0; i < 4; i++) {
#pragma unroll
    for (int j = 0; j < 4; j++) {
      int r = row0 + wr + i * 16 + lg * 4;
      int c = col0 + wc + j * 16 + l15;
#pragma unroll
      for (int q = 0; q < 4; q++) {
        if (OUTF32)
          ((float*)Cout)[(size_t)(r + q) * N + c] = acc[i][j][q];
        else
          ((bf16_t*)Cout)[(size_t)(r + q) * N + c] = (bf16_t)acc[i][j][q];
      }
    }
  }
}

// ---------------- RoPE (interleaved), in-place on qkv submatrix ------------
__global__ __launch_bounds__(256) void k_rope(bf16_t* __restrict__ buf,
                                              const float* __restrict__ cosT,
                                              const float* __restrict__ sinT,
                                              int ncols, float scale) {
  int idx = blockIdx.x * 256 + threadIdx.x;
  int perrow = ncols >> 3;
  int row = idx / perrow;
  int c8 = (idx - row * perrow) << 3;
  int s = row & (S_LEN - 1);
  int p0 = (c8 & (HD - 1)) >> 1;
  bf16_t* p = buf + (size_t)row * QKVN + c8;
  bf16x8_t v = *(const bf16x8_t*)p;
  bf16x8_t r;
#pragma unroll
  for (int t = 0; t < 4; t++) {
    float c = cosT[s * 64 + p0 + t];
    float sn = sinT[s * 64 + p0 + t];
    float te = (float)v[2 * t], to = (float)v[2 * t + 1];
    r[2 * t] = (bf16_t)((te * c - to * sn) * scale);
    r[2 * t + 1] = (bf16_t)((to * c + te * sn) * scale);
  }
  *(bf16x8_t*)p = r;
}

// ---------------- V -> Vt relayout: vt[b][kvh][d][s] -----------------------
__global__ __launch_bounds__(256) void k_vt(const bf16_t* __restrict__ qkv,
                                            bf16_t* __restrict__ vt) {
  __shared__ bf16_t t[32][33];
  int s0 = blockIdx.x * 32;
  int dt = (blockIdx.y & 3) * 32;
  int h = blockIdx.y >> 2;
  int b = blockIdx.z;
  int tx = threadIdx.x & 31, ty = threadIdx.x >> 5;
#pragma unroll
  for (int rr = ty; rr < 32; rr += 8)
    t[rr][tx] = qkv[(size_t)(b * S_LEN + s0 + rr) * QKVN + VOFF + h * HD + dt + tx];
  __syncthreads();
#pragma unroll
  for (int rr = ty; rr < 32; rr += 8)
    vt[((size_t)((b * NKVH + h) * HD + dt + rr)) * S_LEN + s0 + tx] = t[tx][rr];
}

// ---------------- flash attention: 4 waves, QBLK=64, 2-phase pipeline ------
// 1024 blocks, one 64-row q-tile each; dispatch order longest-first
// (qg = 31 - idx>>5) so the HW queue backfills short blocks behind long ones
// (LPT -> ~uniform CU makespan). bh = idx&31 keeps co-resident blocks on the
// same (b,h) -> shared K/V in L2. K/V double-buffered in LDS; next tile's
// global_load_lds issued BEFORE computing current tile (2-phase, T3-min).
// Softmax in base-2 domain (log2e folded into Q scale) with defer-max THR=8.
__global__ __launch_bounds__(256, 2) void k_attn(const bf16_t* __restrict__ qkv,
                                                 const bf16_t* __restrict__ vt,
                                                 bf16_t* __restrict__ ctx) {
  __shared__ bf16_t Ks[2 * 64 * 128];   // 2 x 16 KB, swizzled [kv][d]
  __shared__ bf16_t Vs[2 * 128 * 64];   // 2 x 16 KB, swizzled [d][kv]
  __shared__ bf16_t plds[4][16 * 72];

  int tid = threadIdx.x;
  int lane = tid & 63, wid = tid >> 6;
  int idx = blockIdx.x;
  int bh = idx & 31;
  int qg = 31 - (idx >> 5);        // longest-first dispatch
  int b = bh >> 4, h = bh & 15;
  int kvh = h >> 2;
  int q0 = qg * 64 + wid * 16;
  int l15 = lane & 15, lg = lane >> 4;

  const bf16_t* Kbase = qkv + (size_t)(b * S_LEN) * QKVN + KOFF + kvh * HD;
  const bf16_t* Vbase = vt + (size_t)(b * NKVH + kvh) * HD * S_LEN;

  // Q fragments (16 rows x 128) -> regs (RoPE'd, scaled by rsqrt(D)*log2e)
  const bf16_t* Qp = qkv + (size_t)(b * S_LEN + q0 + l15) * QKVN + h * HD + lg * 8;
  bf16x8_t aq[4];
#pragma unroll
  for (int kk = 0; kk < 4; kk++) aq[kk] = *(const bf16x8_t*)(Qp + kk * 32);

  // per-thread staging slots (tid-constant; inverse-swizzled global source)
  int Ls[4], Lk[4], Lv[4];
#pragma unroll
  for (int u = 0; u < 4; u++) {
    int L = u * 4096 + tid * 16;
    Ls[u] = L >> 1;                       // LDS element offset
    Lk[u] = L ^ (((L >> 8) & 7) << 4);    // K: row stride 256B
    Lv[u] = L ^ (((L >> 7) & 7) << 4);    // V: row stride 128B
  }

  f32x4_t o[8];
#pragma unroll
  for (int j = 0; j < 8; j++) o[j] = zero4();
  float m[4], lsum[4];
#pragma unroll
  for (int i = 0; i < 4; i++) { m[i] = -INFINITY; lsum[i] = 0.f; }

  bf16_t* pbuf = &plds[wid][0];
  int xr = (l15 & 7) << 4;
  int ntiles = qg + 1;

  // prologue: stage tile 0 into buffer 0
#pragma unroll
  for (int u = 0; u < 4; u++) {
    gload_lds16(Kbase + (size_t)(Lk[u] >> 8) * QKVN + ((Lk[u] & 255) >> 1), Ks + Ls[u]);
    gload_lds16(Vbase + (size_t)(Lv[u] >> 7) * S_LEN + ((Lv[u] & 127) >> 1), Vs + Ls[u]);
  }
  __syncthreads();

  for (int t = 0; t < ntiles; t++) {
    int kv0 = t * 64;
    // 2-phase: issue next tile's DMA first, compute current, then barrier
    if (t + 1 < ntiles) {
      const bf16_t* Kn = Kbase + (size_t)(kv0 + 64) * QKVN;
      const bf16_t* Vn = Vbase + kv0 + 64;
      int bo = ((t + 1) & 1) * 8192;
#pragma unroll
      for (int u = 0; u < 4; u++) {
        gload_lds16(Kn + (size_t)(Lk[u] >> 8) * QKVN + ((Lk[u] & 255) >> 1), Ks + bo + Ls[u]);
        gload_lds16(Vn + (size_t)(Lv[u] >> 7) * S_LEN + ((Lv[u] & 127) >> 1), Vs + bo + Ls[u]);
      }
    }
    const char* Kb = (const char*)Ks + (t & 1) * 16384;
    const char* Vb = (const char*)Vs + (t & 1) * 16384;

    // ---- QK^T ----
    f32x4_t sacc[4];
#pragma unroll
    for (int cg = 0; cg < 4; cg++) sacc[cg] = zero4();
#pragma unroll
    for (int cg = 0; cg < 4; cg++) {
#pragma unroll
      for (int kk = 0; kk < 4; kk++) {
        int boff = ((cg * 16 + l15) * 256 + kk * 64 + lg * 16) ^ xr;
        bf16x8_t bk = *(const bf16x8_t*)(Kb + boff);
        sacc[cg] = __builtin_amdgcn_mfma_f32_16x16x32_bf16(aq[kk], bk, sacc[cg], 0, 0, 0);
      }
    }
    if (kv0 + 63 > q0) {
#pragma unroll
      for (int cg = 0; cg < 4; cg++) {
        int col = kv0 + cg * 16 + l15;
#pragma unroll
        for (int i = 0; i < 4; i++) {
          int row = q0 + lg * 4 + i;
          if (col > row) sacc[cg][i] = -1e30f;
        }
      }
    }
    // ---- online softmax (base-2, defer-max) ----
    float pmax[4];
#pragma unroll
    for (int i = 0; i < 4; i++) {
      float v = fmaxf(fmaxf(sacc[0][i], sacc[1][i]), fmaxf(sacc[2][i], sacc[3][i]));
      v = fmaxf(v, __shfl_xor(v, 1));
      v = fmaxf(v, __shfl_xor(v, 2));
      v = fmaxf(v, __shfl_xor(v, 4));
      v = fmaxf(v, __shfl_xor(v, 8));
      pmax[i] = v;
    }
    float dm = fmaxf(fmaxf(pmax[0] - m[0], pmax[1] - m[1]),
                     fmaxf(pmax[2] - m[2], pmax[3] - m[3]));
    if (__any(dm > 8.0f)) {
#pragma unroll
      for (int i = 0; i < 4; i++) {
        float nm = fmaxf(m[i], pmax[i]);
        float sc = fexp2(m[i] - nm);
        m[i] = nm;
        lsum[i] *= sc;
#pragma unroll
        for (int j = 0; j < 8; j++) o[j][i] *= sc;
      }
    }
#pragma unroll
    for (int cg = 0; cg < 4; cg++)
#pragma unroll
      for (int i = 0; i < 4; i++) sacc[cg][i] = fexp2(sacc[cg][i] - m[i]);
#pragma unroll
    for (int i = 0; i < 4; i++) {
      float s = sacc[0][i] + sacc[1][i] + sacc[2][i] + sacc[3][i];
      s += __shfl_xor(s, 1);
      s += __shfl_xor(s, 2);
      s += __shfl_xor(s, 4);
      s += __shfl_xor(s, 8);
      lsum[i] += s;
    }
    // ---- P -> per-wave LDS -> A-fragments ----
#pragma unroll
    for (int cg = 0; cg < 4; cg++)
#pragma unroll
      for (int i = 0; i < 4; i++)
        pbuf[(lg * 4 + i) * 72 + cg * 16 + l15] = (bf16_t)sacc[cg][i];
    __builtin_amdgcn_wave_barrier();
    bf16x8_t pa0 = *(const bf16x8_t*)(pbuf + l15 * 72 + lg * 8);
    bf16x8_t pa1 = *(const bf16x8_t*)(pbuf + l15 * 72 + 32 + lg * 8);
    __builtin_amdgcn_wave_barrier();
    // ---- P.V ----
#pragma unroll
    for (int j = 0; j < 8; j++) {
      int d = j * 16 + l15;
      int bo0 = (d * 128 + lg * 16) ^ xr;
      int bo1 = (d * 128 + 64 + lg * 16) ^ xr;
      o[j] = __builtin_amdgcn_mfma_f32_16x16x32_bf16(
          pa0, *(const bf16x8_t*)(Vb + bo0), o[j], 0, 0, 0);
      o[j] = __builtin_amdgcn_mfma_f32_16x16x32_bf16(
          pa1, *(const bf16x8_t*)(Vb + bo1), o[j], 0, 0, 0);
    }
    __syncthreads();   // next tile's DMA drained (implicit vmcnt(0)), buffers safe
  }

  bf16_t* Cp = ctx + (size_t)(b * S_LEN + q0) * KOFF + h * HD;
#pragma unroll
  for (int i = 0; i < 4; i++) {
    float inv = 1.f / lsum[i];
    int row = lg * 4 + i;
#pragma unroll
    for (int j = 0; j < 8; j++)
      Cp[(size_t)row * KOFF + j * 16 + l15] = (bf16_t)(o[j][i] * inv);
  }
}

extern "C" void kernel_launch(void* const* d_in, const int* in_sizes, int n_in,
                              void* d_out, int out_size, void* d_ws, size_t ws_size,
                              hipStream_t stream) {
  const float* x = (const float*)d_in[0];
  const float* wq = (const float*)d_in[1];
  const float* wk = (const float*)d_in[2];
  const float* wv = (const float*)d_in[3];
  const float* wo = (const float*)d_in[4];
  const float* cosT = (const float*)d_in[5];
  const float* sinT = (const float*)d_in[6];

  bf16_t* xb = (bf16_t*)d_ws;                          // 4096x2048 (later reused as ctx)
  bf16_t* wqkvT = xb + (size_t)MROWS * HIDW;           // 3072x2048
  bf16_t* woT = wqkvT + (size_t)QKVN * HIDW;           // 2048x2048
  bf16_t* qkv = woT + (size_t)HIDW * HIDW;             // 4096x3072
  bf16_t* vtb = qkv + (size_t)MROWS * QKVN;            // 2*4*128*2048

  // 1) convert x
  k_cvt8<<<MROWS * HIDW / 8 / 256, 256, 0, stream>>>(x, xb, MROWS * HIDW / 8);
  // 2) weight transposes (f32 -> bf16, [K][N] -> [N][K])
  k_tr_cvt<<<dim3(KOFF / 32, HIDW / 32), 256, 0, stream>>>(wq, wqkvT, HIDW, KOFF);
  k_tr_cvt<<<dim3((NKVH * HD) / 32, HIDW / 32), 256, 0, stream>>>(
      wk, wqkvT + (size_t)KOFF * HIDW, HIDW, NKVH * HD);
  k_tr_cvt<<<dim3((NKVH * HD) / 32, HIDW / 32), 256, 0, stream>>>(
      wv, wqkvT + (size_t)VOFF * HIDW, HIDW, NKVH * HD);
  k_tr_cvt<<<dim3(HIDW / 32, KOFF / 32), 256, 0, stream>>>(wo, woT, KOFF, HIDW);
  // 3) QKV projection
  k_gemm_bt<0><<<dim3(MROWS / 128, QKVN / 128), 256, 0, stream>>>(
      xb, wqkvT, qkv, MROWS, QKVN, HIDW);
  // 4) RoPE on q (fold rsqrt(D) * log2e for base-2 softmax) and k
  k_rope<<<MROWS * KOFF / 8 / 256, 256, 0, stream>>>(
      qkv, cosT, sinT, KOFF, 0.08838834764831845f * 1.4426950408889634f);
  k_rope<<<MROWS * (NKVH * HD) / 8 / 256, 256, 0, stream>>>(qkv + KOFF, cosT, sinT,
                                                            NKVH * HD, 1.0f);
  // 5) V transpose
  k_vt<<<dim3(S_LEN / 32, 4 * NKVH, NB), 256, 0, stream>>>(qkv, vtb);
  // 6) attention (ctx written into xb region — xb no longer needed)
  k_attn<<<32 * 32, 256, 0, stream>>>(qkv, vtb, xb);
  // 7) output projection -> f32 d_out
  k_gemm_bt<1><<<dim3(MROWS / 128, HIDW / 128), 256, 0, stream>>>(
      xb, woT, d_out, MROWS, HIDW, KOFF);
}

// Round 5
// 255.305 us; speedup vs baseline: 3.1116x; 1.0427x over previous
//
#include <hip/hip_runtime.h>
#include <hip/hip_bf16.h>
#include <math.h>

#define S_LEN 2048
#define HIDW 2048
#define NHEAD 16
#define NKVH 4
#define HD 128
#define NB 2
#define MROWS (NB * S_LEN)                 // 4096
#define QKVN (NHEAD * HD + 2 * NKVH * HD)  // 3072
#define KOFF (NHEAD * HD)                  // 2048
#define VOFF (NHEAD * HD + NKVH * HD)      // 2560

typedef __bf16 bf16_t;
typedef __bf16 bf16x8_t __attribute__((ext_vector_type(8)));
typedef float f32x4_t __attribute__((ext_vector_type(4)));

__device__ __forceinline__ void gload_lds16(const bf16_t* g, bf16_t* l) {
  __builtin_amdgcn_global_load_lds(
      (const __attribute__((address_space(1))) void*)g,
      (__attribute__((address_space(3))) void*)l, 16, 0, 0);
}

__device__ __forceinline__ f32x4_t zero4() {
  f32x4_t z = {0.f, 0.f, 0.f, 0.f};
  return z;
}

__device__ __forceinline__ float fexp2(float x) {
#if __has_builtin(__builtin_amdgcn_exp2f)
  return __builtin_amdgcn_exp2f(x);
#else
  return exp2f(x);
#endif
}

// ---------------- convert x (f32 -> bf16), 8 elems/thread ----------------
__global__ __launch_bounds__(256) void k_cvt8(const float* __restrict__ in,
                                              bf16_t* __restrict__ out, int n8) {
  int i = blockIdx.x * 256 + threadIdx.x;
  if (i >= n8) return;
  const float4* p = (const float4*)(in + (size_t)i * 8);
  float4 a = p[0], b = p[1];
  bf16x8_t r;
  r[0] = (bf16_t)a.x; r[1] = (bf16_t)a.y; r[2] = (bf16_t)a.z; r[3] = (bf16_t)a.w;
  r[4] = (bf16_t)b.x; r[5] = (bf16_t)b.y; r[6] = (bf16_t)b.z; r[7] = (bf16_t)b.w;
  *(bf16x8_t*)(out + (size_t)i * 8) = r;
}

// ---------------- transpose + convert: in f32 [R][C] -> out bf16 [C][R] ----
__global__ __launch_bounds__(256) void k_tr_cvt(const float* __restrict__ in,
                                                bf16_t* __restrict__ out, int R, int C) {
  __shared__ float t[32][33];
  int c0 = blockIdx.x * 32, r0 = blockIdx.y * 32;
  int tx = threadIdx.x & 31, ty = threadIdx.x >> 5;
#pragma unroll
  for (int rr = ty; rr < 32; rr += 8) t[rr][tx] = in[(size_t)(r0 + rr) * C + c0 + tx];
  __syncthreads();
#pragma unroll
  for (int rr = ty; rr < 32; rr += 8)
    out[(size_t)(c0 + rr) * R + r0 + tx] = (bf16_t)t[tx][rr];
}

// ---------------- GEMM 256x256 tile, BK=64, 8 waves, phase-interleaved -----
// C[M][N] = A[M][K] * Bt[N][K]^T. Double-buffered 128 KiB LDS; per K-tile 4
// quadrant-phases: {ds_read frags | stage <=3 gloads of next tile | s_barrier
// | setprio(1) 16 MFMA setprio(0) | s_barrier}; one vmcnt(0) at buffer swap.
// G4 XOR swizzle (byte ^= (row&7)<<4) both sides: inverse-swizzled global
// staging source + swizzled ds_read -> conflict-free b128 at 128B row stride.
template <int OUTF32>
__global__ __launch_bounds__(512, 2) void k_gemm256(const bf16_t* __restrict__ A,
                                                    const bf16_t* __restrict__ Bt,
                                                    void* __restrict__ Cout,
                                                    int M, int N, int K, int nby) {
  __shared__ bf16_t As[2][256 * 64];
  __shared__ bf16_t Bs[2][256 * 64];

  int tid = threadIdx.x;
  int lane = tid & 63, wid = tid >> 6;
  int l15 = lane & 15, lg = lane >> 4;
  int wrb = (wid >> 2) * 128;   // wave M-offset (2 M-halves)
  int wcb = (wid & 3) * 64;     // wave N-offset (4 N-quarters)

  // XCD-aware bijective block swizzle (nwg % 8 == 0); by fastest -> same-XCD
  // blocks share the A-panel in their L2.
  int nwg = gridDim.x;
  int qx = nwg >> 3;
  int lin = blockIdx.x;
  int wg = (lin & 7) * qx + (lin >> 3);
  int row0 = (wg / nby) * 256, col0 = (wg % nby) * 256;

  // staging source: row = srow + u*64, col identical for all 4 passes
  // (inverse of the (row&7)<<4 byte-XOR since row&7 == srow&7 for all u)
  int srow = tid >> 3;
  int scol = ((tid & 7) ^ (srow & 7)) * 8;
  const bf16_t* Ag = A + (size_t)(row0 + srow) * K + scol;
  const bf16_t* Bg = Bt + (size_t)(col0 + srow) * K + scol;

  f32x4_t acc[8][4];
#pragma unroll
  for (int i = 0; i < 8; i++)
#pragma unroll
    for (int j = 0; j < 4; j++) acc[i][j] = zero4();

  int xr = (l15 & 7) << 4;

  // prologue: stage tile 0 -> buf 0, full drain (allowed once)
#pragma unroll
  for (int u = 0; u < 4; u++) {
    gload_lds16(Ag + (size_t)u * 64 * K, As[0] + u * 4096 + tid * 8);
    gload_lds16(Bg + (size_t)u * 64 * K, Bs[0] + u * 4096 + tid * 8);
  }
  asm volatile("s_waitcnt vmcnt(0)" ::: "memory");
  __builtin_amdgcn_s_barrier();
  __builtin_amdgcn_sched_barrier(0);

  int nk = K >> 6;
  for (int t = 0; t < nk; t++) {
    int cur = t & 1;
    const char* Ac = (const char*)As[cur];
    const char* Bc = (const char*)Bs[cur];
    bf16_t* An = As[cur ^ 1];
    bf16_t* Bn = Bs[cur ^ 1];
    const bf16_t* Agn = Ag + (size_t)(t + 1) * 64;
    const bf16_t* Bgn = Bg + (size_t)(t + 1) * 64;
    bool pf = (t + 1 < nk);

    bf16x8_t af[4][2];   // A-frags reused across the two N-half phases
#pragma unroll
    for (int ph = 0; ph < 4; ph++) {
      const int mh = ph >> 1, nh = ph & 1;
      if (nh == 0) {
#pragma unroll
        for (int i = 0; i < 4; i++) {
          int row = wrb + (mh * 4 + i) * 16 + l15;
#pragma unroll
          for (int kk = 0; kk < 2; kk++)
            af[i][kk] = *(const bf16x8_t*)(Ac + ((row * 128 + kk * 64 + lg * 16) ^ xr));
        }
      }
      bf16x8_t bfr[2][2];
#pragma unroll
      for (int j = 0; j < 2; j++) {
        int rowb = wcb + (nh * 2 + j) * 16 + l15;
#pragma unroll
        for (int kk = 0; kk < 2; kk++)
          bfr[j][kk] = *(const bf16x8_t*)(Bc + ((rowb * 128 + kk * 64 + lg * 16) ^ xr));
      }
      // stage next tile: 3+3+2 loads over phases 0-2 (phase 3 issues none so
      // the last loads get a full phase of MFMA+ds_read to hide under)
      if (pf) {
        if (ph == 0) {
          gload_lds16(Agn, An + tid * 8);
          gload_lds16(Agn + (size_t)64 * K, An + 4096 + tid * 8);
          gload_lds16(Bgn, Bn + tid * 8);
        } else if (ph == 1) {
          gload_lds16(Agn + (size_t)128 * K, An + 8192 + tid * 8);
          gload_lds16(Agn + (size_t)192 * K, An + 12288 + tid * 8);
          gload_lds16(Bgn + (size_t)64 * K, Bn + 4096 + tid * 8);
        } else if (ph == 2) {
          gload_lds16(Bgn + (size_t)128 * K, Bn + 8192 + tid * 8);
          gload_lds16(Bgn + (size_t)192 * K, Bn + 12288 + tid * 8);
        }
      }
      __builtin_amdgcn_s_barrier();
      __builtin_amdgcn_s_setprio(1);
#pragma unroll
      for (int i = 0; i < 4; i++)
#pragma unroll
        for (int j = 0; j < 2; j++)
#pragma unroll
          for (int kk = 0; kk < 2; kk++)
            acc[mh * 4 + i][nh * 2 + j] = __builtin_amdgcn_mfma_f32_16x16x32_bf16(
                af[i][kk], bfr[j][kk], acc[mh * 4 + i][nh * 2 + j], 0, 0, 0);
      __builtin_amdgcn_s_setprio(0);
      if (ph < 3) __builtin_amdgcn_s_barrier();
    }
    // buffer swap: own loads complete + all threads past it -> staged tile
    // visible block-wide. (Counted vmcnt would need a 3rd buffer; LDS-capped.)
    if (pf) asm volatile("s_waitcnt vmcnt(0)" ::: "memory");
    __builtin_amdgcn_s_barrier();
    __builtin_amdgcn_sched_barrier(0);
  }

#pragma unroll
  for (int i = 0; i < 8; i++) {
#pragma unroll
    for (int j = 0; j < 4; j++) {
      int r = row0 + wrb + i * 16 + lg * 4;
      int c = col0 + wcb + j * 16 + l15;
#pragma unroll
      for (int qd = 0; qd < 4; qd++) {
        if (OUTF32)
          ((float*)Cout)[(size_t)(r + qd) * N + c] = acc[i][j][qd];
        else
          ((bf16_t*)Cout)[(size_t)(r + qd) * N + c] = (bf16_t)acc[i][j][qd];
      }
    }
  }
}

// ---------------- RoPE (interleaved), in-place on qkv submatrix ------------
__global__ __launch_bounds__(256) void k_rope(bf16_t* __restrict__ buf,
                                              const float* __restrict__ cosT,
                                              const float* __restrict__ sinT,
                                              int ncols, float scale) {
  int idx = blockIdx.x * 256 + threadIdx.x;
  int perrow = ncols >> 3;
  int row = idx / perrow;
  int c8 = (idx - row * perrow) << 3;
  int s = row & (S_LEN - 1);
  int p0 = (c8 & (HD - 1)) >> 1;
  bf16_t* p = buf + (size_t)row * QKVN + c8;
  bf16x8_t v = *(const bf16x8_t*)p;
  bf16x8_t r;
#pragma unroll
  for (int t = 0; t < 4; t++) {
    float c = cosT[s * 64 + p0 + t];
    float sn = sinT[s * 64 + p0 + t];
    float te = (float)v[2 * t], to = (float)v[2 * t + 1];
    r[2 * t] = (bf16_t)((te * c - to * sn) * scale);
    r[2 * t + 1] = (bf16_t)((to * c + te * sn) * scale);
  }
  *(bf16x8_t*)p = r;
}

// ---------------- V -> Vt relayout: vt[b][kvh][d][s] -----------------------
__global__ __launch_bounds__(256) void k_vt(const bf16_t* __restrict__ qkv,
                                            bf16_t* __restrict__ vt) {
  __shared__ bf16_t t[32][33];
  int s0 = blockIdx.x * 32;
  int dt = (blockIdx.y & 3) * 32;
  int h = blockIdx.y >> 2;
  int b = blockIdx.z;
  int tx = threadIdx.x & 31, ty = threadIdx.x >> 5;
#pragma unroll
  for (int rr = ty; rr < 32; rr += 8)
    t[rr][tx] = qkv[(size_t)(b * S_LEN + s0 + rr) * QKVN + VOFF + h * HD + dt + tx];
  __syncthreads();
#pragma unroll
  for (int rr = ty; rr < 32; rr += 8)
    vt[((size_t)((b * NKVH + h) * HD + dt + rr)) * S_LEN + s0 + tx] = t[tx][rr];
}

// ---------------- flash attention: 4 waves, QBLK=64, 2-phase pipeline ------
__global__ __launch_bounds__(256, 2) void k_attn(const bf16_t* __restrict__ qkv,
                                                 const bf16_t* __restrict__ vt,
                                                 bf16_t* __restrict__ ctx) {
  __shared__ bf16_t Ks[2 * 64 * 128];   // 2 x 16 KB, swizzled [kv][d]
  __shared__ bf16_t Vs[2 * 128 * 64];   // 2 x 16 KB, swizzled [d][kv]
  __shared__ bf16_t plds[4][16 * 72];

  int tid = threadIdx.x;
  int lane = tid & 63, wid = tid >> 6;
  int idx = blockIdx.x;
  int bh = idx & 31;
  int qg = 31 - (idx >> 5);        // longest-first dispatch
  int b = bh >> 4, h = bh & 15;
  int kvh = h >> 2;
  int q0 = qg * 64 + wid * 16;
  int l15 = lane & 15, lg = lane >> 4;

  const bf16_t* Kbase = qkv + (size_t)(b * S_LEN) * QKVN + KOFF + kvh * HD;
  const bf16_t* Vbase = vt + (size_t)(b * NKVH + kvh) * HD * S_LEN;

  const bf16_t* Qp = qkv + (size_t)(b * S_LEN + q0 + l15) * QKVN + h * HD + lg * 8;
  bf16x8_t aq[4];
#pragma unroll
  for (int kk = 0; kk < 4; kk++) aq[kk] = *(const bf16x8_t*)(Qp + kk * 32);

  int Ls[4], Lk[4], Lv[4];
#pragma unroll
  for (int u = 0; u < 4; u++) {
    int L = u * 4096 + tid * 16;
    Ls[u] = L >> 1;
    Lk[u] = L ^ (((L >> 8) & 7) << 4);
    Lv[u] = L ^ (((L >> 7) & 7) << 4);
  }

  f32x4_t o[8];
#pragma unroll
  for (int j = 0; j < 8; j++) o[j] = zero4();
  float m[4], lsum[4];
#pragma unroll
  for (int i = 0; i < 4; i++) { m[i] = -INFINITY; lsum[i] = 0.f; }

  bf16_t* pbuf = &plds[wid][0];
  int xr = (l15 & 7) << 4;
  int ntiles = qg + 1;

#pragma unroll
  for (int u = 0; u < 4; u++) {
    gload_lds16(Kbase + (size_t)(Lk[u] >> 8) * QKVN + ((Lk[u] & 255) >> 1), Ks + Ls[u]);
    gload_lds16(Vbase + (size_t)(Lv[u] >> 7) * S_LEN + ((Lv[u] & 127) >> 1), Vs + Ls[u]);
  }
  __syncthreads();

  for (int t = 0; t < ntiles; t++) {
    int kv0 = t * 64;
    if (t + 1 < ntiles) {
      const bf16_t* Kn = Kbase + (size_t)(kv0 + 64) * QKVN;
      const bf16_t* Vn = Vbase + kv0 + 64;
      int bo = ((t + 1) & 1) * 8192;
#pragma unroll
      for (int u = 0; u < 4; u++) {
        gload_lds16(Kn + (size_t)(Lk[u] >> 8) * QKVN + ((Lk[u] & 255) >> 1), Ks + bo + Ls[u]);
        gload_lds16(Vn + (size_t)(Lv[u] >> 7) * S_LEN + ((Lv[u] & 127) >> 1), Vs + bo + Ls[u]);
      }
    }
    const char* Kb = (const char*)Ks + (t & 1) * 16384;
    const char* Vb = (const char*)Vs + (t & 1) * 16384;

    f32x4_t sacc[4];
#pragma unroll
    for (int cg = 0; cg < 4; cg++) sacc[cg] = zero4();
#pragma unroll
    for (int cg = 0; cg < 4; cg++) {
#pragma unroll
      for (int kk = 0; kk < 4; kk++) {
        int boff = ((cg * 16 + l15) * 256 + kk * 64 + lg * 16) ^ xr;
        bf16x8_t bk = *(const bf16x8_t*)(Kb + boff);
        sacc[cg] = __builtin_amdgcn_mfma_f32_16x16x32_bf16(aq[kk], bk, sacc[cg], 0, 0, 0);
      }
    }
    if (kv0 + 63 > q0) {
#pragma unroll
      for (int cg = 0; cg < 4; cg++) {
        int col = kv0 + cg * 16 + l15;
#pragma unroll
        for (int i = 0; i < 4; i++) {
          int row = q0 + lg * 4 + i;
          if (col > row) sacc[cg][i] = -1e30f;
        }
      }
    }
    float pmax[4];
#pragma unroll
    for (int i = 0; i < 4; i++) {
      float v = fmaxf(fmaxf(sacc[0][i], sacc[1][i]), fmaxf(sacc[2][i], sacc[3][i]));
      v = fmaxf(v, __shfl_xor(v, 1));
      v = fmaxf(v, __shfl_xor(v, 2));
      v = fmaxf(v, __shfl_xor(v, 4));
      v = fmaxf(v, __shfl_xor(v, 8));
      pmax[i] = v;
    }
    float dm = fmaxf(fmaxf(pmax[0] - m[0], pmax[1] - m[1]),
                     fmaxf(pmax[2] - m[2], pmax[3] - m[3]));
    if (__any(dm > 8.0f)) {
#pragma unroll
      for (int i = 0; i < 4; i++) {
        float nm = fmaxf(m[i], pmax[i]);
        float sc = fexp2(m[i] - nm);
        m[i] = nm;
        lsum[i] *= sc;
#pragma unroll
        for (int j = 0; j < 8; j++) o[j][i] *= sc;
      }
    }
#pragma unroll
    for (int cg = 0; cg < 4; cg++)
#pragma unroll
      for (int i = 0; i < 4; i++) sacc[cg][i] = fexp2(sacc[cg][i] - m[i]);
#pragma unroll
    for (int i = 0; i < 4; i++) {
      float s = sacc[0][i] + sacc[1][i] + sacc[2][i] + sacc[3][i];
      s += __shfl_xor(s, 1);
      s += __shfl_xor(s, 2);
      s += __shfl_xor(s, 4);
      s += __shfl_xor(s, 8);
      lsum[i] += s;
    }
#pragma unroll
    for (int cg = 0; cg < 4; cg++)
#pragma unroll
      for (int i = 0; i < 4; i++)
        pbuf[(lg * 4 + i) * 72 + cg * 16 + l15] = (bf16_t)sacc[cg][i];
    __builtin_amdgcn_wave_barrier();
    bf16x8_t pa0 = *(const bf16x8_t*)(pbuf + l15 * 72 + lg * 8);
    bf16x8_t pa1 = *(const bf16x8_t*)(pbuf + l15 * 72 + 32 + lg * 8);
    __builtin_amdgcn_wave_barrier();
#pragma unroll
    for (int j = 0; j < 8; j++) {
      int d = j * 16 + l15;
      int bo0 = (d * 128 + lg * 16) ^ xr;
      int bo1 = (d * 128 + 64 + lg * 16) ^ xr;
      o[j] = __builtin_amdgcn_mfma_f32_16x16x32_bf16(
          pa0, *(const bf16x8_t*)(Vb + bo0), o[j], 0, 0, 0);
      o[j] = __builtin_amdgcn_mfma_f32_16x16x32_bf16(
          pa1, *(const bf16x8_t*)(Vb + bo1), o[j], 0, 0, 0);
    }
    __syncthreads();
  }

  bf16_t* Cp = ctx + (size_t)(b * S_LEN + q0) * KOFF + h * HD;
#pragma unroll
  for (int i = 0; i < 4; i++) {
    float inv = 1.f / lsum[i];
    int row = lg * 4 + i;
#pragma unroll
    for (int j = 0; j < 8; j++)
      Cp[(size_t)row * KOFF + j * 16 + l15] = (bf16_t)(o[j][i] * inv);
  }
}

extern "C" void kernel_launch(void* const* d_in, const int* in_sizes, int n_in,
                              void* d_out, int out_size, void* d_ws, size_t ws_size,
                              hipStream_t stream) {
  const float* x = (const float*)d_in[0];
  const float* wq = (const float*)d_in[1];
  const float* wk = (const float*)d_in[2];
  const float* wv = (const float*)d_in[3];
  const float* wo = (const float*)d_in[4];
  const float* cosT = (const float*)d_in[5];
  const float* sinT = (const float*)d_in[6];

  bf16_t* xb = (bf16_t*)d_ws;                          // 4096x2048 (later reused as ctx)
  bf16_t* wqkvT = xb + (size_t)MROWS * HIDW;           // 3072x2048
  bf16_t* woT = wqkvT + (size_t)QKVN * HIDW;           // 2048x2048
  bf16_t* qkv = woT + (size_t)HIDW * HIDW;             // 4096x3072
  bf16_t* vtb = qkv + (size_t)MROWS * QKVN;            // 2*4*128*2048

  // 1) convert x
  k_cvt8<<<MROWS * HIDW / 8 / 256, 256, 0, stream>>>(x, xb, MROWS * HIDW / 8);
  // 2) weight transposes (f32 -> bf16, [K][N] -> [N][K])
  k_tr_cvt<<<dim3(KOFF / 32, HIDW / 32), 256, 0, stream>>>(wq, wqkvT, HIDW, KOFF);
  k_tr_cvt<<<dim3((NKVH * HD) / 32, HIDW / 32), 256, 0, stream>>>(
      wk, wqkvT + (size_t)KOFF * HIDW, HIDW, NKVH * HD);
  k_tr_cvt<<<dim3((NKVH * HD) / 32, HIDW / 32), 256, 0, stream>>>(
      wv, wqkvT + (size_t)VOFF * HIDW, HIDW, NKVH * HD);
  k_tr_cvt<<<dim3(HIDW / 32, KOFF / 32), 256, 0, stream>>>(wo, woT, KOFF, HIDW);
  // 3) QKV projection (256^2 tile, 192 blocks)
  k_gemm256<0><<<(MROWS / 256) * (QKVN / 256), 512, 0, stream>>>(
      xb, wqkvT, qkv, MROWS, QKVN, HIDW, QKVN / 256);
  // 4) RoPE on q (fold rsqrt(D) * log2e for base-2 softmax) and k
  k_rope<<<MROWS * KOFF / 8 / 256, 256, 0, stream>>>(
      qkv, cosT, sinT, KOFF, 0.08838834764831845f * 1.4426950408889634f);
  k_rope<<<MROWS * (NKVH * HD) / 8 / 256, 256, 0, stream>>>(qkv + KOFF, cosT, sinT,
                                                            NKVH * HD, 1.0f);
  // 5) V transpose
  k_vt<<<dim3(S_LEN / 32, 4 * NKVH, NB), 256, 0, stream>>>(qkv, vtb);
  // 6) attention (ctx written into xb region — xb no longer needed)
  k_attn<<<32 * 32, 256, 0, stream>>>(qkv, vtb, xb);
  // 7) output projection -> f32 d_out (256^2 tile, 128 blocks)
  k_gemm256<1><<<(MROWS / 256) * (HIDW / 256), 512, 0, stream>>>(
      xb, woT, d_out, MROWS, HIDW, KOFF, HIDW / 256);
}